// Round 4
// baseline (177.487 us; speedup 1.0000x reference)
//
#include <hip/hip_runtime.h>
#include <math.h>

// Problem constants (fixed by setup_inputs): B=4096, T=512, Q=4
#define T_DIM 512
#define GAMMA_F 0.997f
#define EPS_F 1e-3f
// log2(0.997)
#define LOG2_GAMMA (-0.0043345907f)

typedef float v4f __attribute__((ext_vector_type(4)));

__device__ __forceinline__ float inv_rescale_f(float x) {
    float s = (x > 0.f) ? 1.f : ((x < 0.f) ? -1.f : 0.f);
    float sqrt_arg = 1.f + 4.f * EPS_F * (fabsf(x) + 1.f + EPS_F);
    float q = (sqrtf(sqrt_arg) - 1.f) * (1.f / (2.f * EPS_F));
    return s * (q * q - 1.f);
}

__device__ __forceinline__ float rescale_f(float x) {
    return copysignf(sqrtf(fabsf(x) + 1.f) - 1.f, x) + EPS_F * x;
}

// R7: thread-granularity experiment. R0 (22 direct loads) and R6 (LDS row
// staging) ran IDENTICAL (~48 us, 2 TB/s, all pipes idle) despite totally
// different structures => the shared trait is the bottleneck: 2M one-shot
// short-lived threads, each paying one full memory round-trip, no per-thread
// pipelining. All known-good memory-bound kernels on this chip (copy 6.3TB/s,
// RMSNorm 4.9TB/s) use ~2048 blocks x 256 threads with multiple 16B elements
// per thread. This kernel: each thread computes 4 consecutive t outputs;
// window taps t..t+7 live in registers and are reused across the 4
// overlapping 5-tap windows (register halo replaces LDS; no barrier).
// 31 loads / 352B per thread, dwordx4-dominated. Grid 2048x256 covers
// B*T exactly.
__global__ __launch_bounds__(256) void nstep_qloss_kernel(
    const float* __restrict__ cur_q,    // (B,T,4)
    const float* __restrict__ next_q,   // (B,T,4)
    const float* __restrict__ log_p,    // (B,T)
    const float* __restrict__ reward,   // (B,T,4)
    const float* __restrict__ is_done,  // (B,T)
    const float* __restrict__ mask,     // (B,T)
    float* __restrict__ out,            // (B,T,4)
    int BT)
{
    const int cid = blockIdx.x * 256 + threadIdx.x;   // chunk id: 4 t's per chunk
    if (cid * 4 >= BT) return;
    const int b    = cid >> 7;                        // 128 chunks per row
    const int t0   = (cid & 127) << 2;
    const int base = b * T_DIM;

    // clamped halo t-indices u=4..7 (only the t0==508 chunk actually clamps)
    const int h4 = (t0 + 4 < T_DIM) ? t0 + 4 : T_DIM - 1;
    const int h5 = (t0 + 5 < T_DIM) ? t0 + 5 : T_DIM - 1;
    const int h6 = (t0 + 6 < T_DIM) ? t0 + 6 : T_DIM - 1;
    const int h7 = (t0 + 7 < T_DIM) ? t0 + 7 : T_DIM - 1;
    // validity of halo taps (owned taps u=0..3 always valid)
    const float va4 = (t0 + 4 < T_DIM) ? 1.f : 0.f;
    const float va5 = (t0 + 5 < T_DIM) ? 1.f : 0.f;
    const float va6 = (t0 + 6 < T_DIM) ? 1.f : 0.f;
    const float va7 = (t0 + 7 < T_DIM) ? 1.f : 0.f;

    const v4f* rew4 = (const v4f*)reward;
    const v4f* nq4  = (const v4f*)next_q;
    const v4f* cq4  = (const v4f*)cur_q;
    v4f*       out4 = (v4f*)out;

    // ---------------- load block (31 loads, 352B/thread) ----------------
    v4f m_o = *(const v4f*)(mask    + base + t0);   // mask[t0..t0+3]
    v4f d_o = *(const v4f*)(is_done + base + t0);
    v4f p_o = *(const v4f*)(log_p   + base + t0);
    float mh4 = mask[base + h4], mh5 = mask[base + h5], mh6 = mask[base + h6], mh7 = mask[base + h7];
    float dh4 = is_done[base + h4], dh5 = is_done[base + h5], dh6 = is_done[base + h6], dh7 = is_done[base + h7];
    float ph4 = log_p[base + h4], ph5 = log_p[base + h5], ph6 = log_p[base + h6], ph7 = log_p[base + h7];
    v4f r0 = rew4[base + t0];
    v4f r1 = rew4[base + t0 + 1];
    v4f r2 = rew4[base + t0 + 2];
    v4f r3 = rew4[base + t0 + 3];
    v4f r4 = rew4[base + h4];
    v4f r5 = rew4[base + h5];
    v4f r6 = rew4[base + h6];
    v4f r7 = rew4[base + h7];
    v4f n0 = nq4[base + h4];                         // next_q at s4 of t0+j
    v4f n1 = nq4[base + h5];
    v4f n2 = nq4[base + h6];
    v4f n3 = nq4[base + h7];
    v4f c0 = cq4[base + t0];
    v4f c1 = cq4[base + t0 + 1];
    v4f c2 = cq4[base + t0 + 2];
    v4f c3 = cq4[base + t0 + 3];

    // ---------------- per-tap pre-combined operands ----------------
    // m*(1-d) at clamped index (for next_term), u=4..7
    float md4 = mh4 * (1.f - dh4);
    float md5 = mh5 * (1.f - dh5);
    float md6 = mh6 * (1.f - dh6);
    float md7 = mh7 * (1.f - dh7);
    // zeroed (validity-masked) log_p operand lz[u] = val*m*(1-d)*p
    float lz0 = m_o.x * (1.f - d_o.x) * p_o.x;
    float lz1 = m_o.y * (1.f - d_o.y) * p_o.y;
    float lz2 = m_o.z * (1.f - d_o.z) * p_o.z;
    float lz3 = m_o.w * (1.f - d_o.w) * p_o.w;
    float lz4 = va4 * md4 * ph4;
    float lz5 = va5 * md5 * ph5;
    float lz6 = va6 * md6 * ph6;
    float lz7 = va7 * md7 * ph7;
    // zeroed reward operand per needed q-component (q=2 weight 0 -> skipped)
    float w0 = m_o.x, w1 = m_o.y, w2 = m_o.z, w3 = m_o.w;
    float w4 = va4 * mh4, w5 = va5 * mh5, w6 = va6 * mh6, w7 = va7 * mh7;
    float x0 = w0 * r0.x, y0 = w0 * r0.y, z0 = w0 * r0.w;
    float x1 = w1 * r1.x, y1 = w1 * r1.y, z1 = w1 * r1.w;
    float x2 = w2 * r2.x, y2 = w2 * r2.y, z2 = w2 * r2.w;
    float x3 = w3 * r3.x, y3 = w3 * r3.y, z3 = w3 * r3.w;
    float x4 = w4 * r4.x, y4 = w4 * r4.y, z4 = w4 * r4.w;
    float x5 = w5 * r5.x, y5 = w5 * r5.y, z5 = w5 * r5.w;
    float x6 = w6 * r6.x, y6 = w6 * r6.y, z6 = w6 * r6.w;
    float x7 = w7 * r7.x, y7 = w7 * r7.y, z7 = w7 * r7.w;

    const float g1 = GAMMA_F;
    const float g2 = g1 * g1;
    const float g3 = g2 * g1;
    const float g4 = g2 * g2;
    const float LSC = GAMMA_F * (1.f / 3.f);   // extra gamma * inv_num_q

    // ---------------- per-output j = 0..3 ----------------
    // j=0: taps 0..4
    float a0 = x0; a0 = fmaf(g1, x1, a0); a0 = fmaf(g2, x2, a0); a0 = fmaf(g3, x3, a0); a0 = fmaf(g4, x4, a0);
    float b0 = y0; b0 = fmaf(g1, y1, b0); b0 = fmaf(g2, y2, b0); b0 = fmaf(g3, y3, b0); b0 = fmaf(g4, y4, b0);
    float e0 = z0; e0 = fmaf(g1, z1, e0); e0 = fmaf(g2, z2, e0); e0 = fmaf(g3, z3, e0); e0 = fmaf(g4, z4, e0);
    float L0 = lz0; L0 = fmaf(g1, lz1, L0); L0 = fmaf(g2, lz2, L0); L0 = fmaf(g3, lz3, L0); L0 = fmaf(g4, lz4, L0);
    L0 *= LSC;
    // j=1: taps 1..5
    float a1 = x1; a1 = fmaf(g1, x2, a1); a1 = fmaf(g2, x3, a1); a1 = fmaf(g3, x4, a1); a1 = fmaf(g4, x5, a1);
    float b1 = y1; b1 = fmaf(g1, y2, b1); b1 = fmaf(g2, y3, b1); b1 = fmaf(g3, y4, b1); b1 = fmaf(g4, y5, b1);
    float e1 = z1; e1 = fmaf(g1, z2, e1); e1 = fmaf(g2, z3, e1); e1 = fmaf(g3, z4, e1); e1 = fmaf(g4, z5, e1);
    float L1 = lz1; L1 = fmaf(g1, lz2, L1); L1 = fmaf(g2, lz3, L1); L1 = fmaf(g3, lz4, L1); L1 = fmaf(g4, lz5, L1);
    L1 *= LSC;
    // j=2: taps 2..6
    float a2 = x2; a2 = fmaf(g1, x3, a2); a2 = fmaf(g2, x4, a2); a2 = fmaf(g3, x5, a2); a2 = fmaf(g4, x6, a2);
    float b2 = y2; b2 = fmaf(g1, y3, b2); b2 = fmaf(g2, y4, b2); b2 = fmaf(g3, y5, b2); b2 = fmaf(g4, y6, b2);
    float e2 = z2; e2 = fmaf(g1, z3, e2); e2 = fmaf(g2, z4, e2); e2 = fmaf(g3, z5, e2); e2 = fmaf(g4, z6, e2);
    float L2 = lz2; L2 = fmaf(g1, lz3, L2); L2 = fmaf(g2, lz4, L2); L2 = fmaf(g3, lz5, L2); L2 = fmaf(g4, lz6, L2);
    L2 *= LSC;
    // j=3: taps 3..7
    float a3 = x3; a3 = fmaf(g1, x4, a3); a3 = fmaf(g2, x5, a3); a3 = fmaf(g3, x6, a3); a3 = fmaf(g4, x7, a3);
    float b3 = y3; b3 = fmaf(g1, y4, b3); b3 = fmaf(g2, y5, b3); b3 = fmaf(g3, y6, b3); b3 = fmaf(g4, y7, b3);
    float e3 = z3; e3 = fmaf(g1, z4, e3); e3 = fmaf(g2, z5, e3); e3 = fmaf(g3, z6, e3); e3 = fmaf(g4, z7, e3);
    float L3 = lz3; L3 = fmaf(g1, lz4, L3); L3 = fmaf(g2, lz5, L3); L3 = fmaf(g3, lz6, L3); L3 = fmaf(g4, lz7, L3);
    L3 *= LSC;

    // next_term coefficients: gamma^{clamped abs index} * m*(1-d) at that index
    float q0 = exp2f((float)h4 * LOG2_GAMMA) * md4;
    float q1 = exp2f((float)h5 * LOG2_GAMMA) * md5;
    float q2 = exp2f((float)h6 * LOG2_GAMMA) * md6;
    float q3 = exp2f((float)h7 * LOG2_GAMMA) * md7;

    // ---------------- epilogue per output ----------------
    {
        float t0x = rescale_f(a0 + q0 * inv_rescale_f(n0.x) + 1.0f * L0);
        float t0y = rescale_f(b0 + q0 * inv_rescale_f(n0.y) + 2.0f * L0);
        float t0w = rescale_f(e0 + q0 * inv_rescale_f(n0.w) + 0.5f * L0);
        float hm = 0.5f * m_o.x;
        float u0 = c0.x - t0x, u1 = c0.y - t0y, u3 = c0.w - t0w;
        v4f o; o.x = hm * u0 * u0; o.y = hm * 0.5f * u1 * u1; o.z = 0.f; o.w = hm * 2.0f * u3 * u3;
        out4[base + t0] = o;
    }
    {
        float t1x = rescale_f(a1 + q1 * inv_rescale_f(n1.x) + 1.0f * L1);
        float t1y = rescale_f(b1 + q1 * inv_rescale_f(n1.y) + 2.0f * L1);
        float t1w = rescale_f(e1 + q1 * inv_rescale_f(n1.w) + 0.5f * L1);
        float hm = 0.5f * m_o.y;
        float u0 = c1.x - t1x, u1 = c1.y - t1y, u3 = c1.w - t1w;
        v4f o; o.x = hm * u0 * u0; o.y = hm * 0.5f * u1 * u1; o.z = 0.f; o.w = hm * 2.0f * u3 * u3;
        out4[base + t0 + 1] = o;
    }
    {
        float t2x = rescale_f(a2 + q2 * inv_rescale_f(n2.x) + 1.0f * L2);
        float t2y = rescale_f(b2 + q2 * inv_rescale_f(n2.y) + 2.0f * L2);
        float t2w = rescale_f(e2 + q2 * inv_rescale_f(n2.w) + 0.5f * L2);
        float hm = 0.5f * m_o.z;
        float u0 = c2.x - t2x, u1 = c2.y - t2y, u3 = c2.w - t2w;
        v4f o; o.x = hm * u0 * u0; o.y = hm * 0.5f * u1 * u1; o.z = 0.f; o.w = hm * 2.0f * u3 * u3;
        out4[base + t0 + 2] = o;
    }
    {
        float t3x = rescale_f(a3 + q3 * inv_rescale_f(n3.x) + 1.0f * L3);
        float t3y = rescale_f(b3 + q3 * inv_rescale_f(n3.y) + 2.0f * L3);
        float t3w = rescale_f(e3 + q3 * inv_rescale_f(n3.w) + 0.5f * L3);
        float hm = 0.5f * m_o.w;
        float u0 = c3.x - t3x, u1 = c3.y - t3y, u3 = c3.w - t3w;
        v4f o; o.x = hm * u0 * u0; o.y = hm * 0.5f * u1 * u1; o.z = 0.f; o.w = hm * 2.0f * u3 * u3;
        out4[base + t0 + 3] = o;
    }
}

extern "C" void kernel_launch(void* const* d_in, const int* in_sizes, int n_in,
                              void* d_out, int out_size, void* d_ws, size_t ws_size,
                              hipStream_t stream) {
    const float* cur_q   = (const float*)d_in[0];
    const float* next_q  = (const float*)d_in[1];
    const float* log_p   = (const float*)d_in[2];
    const float* reward  = (const float*)d_in[3];
    const float* is_done = (const float*)d_in[4];
    const float* mask    = (const float*)d_in[5];
    float* out = (float*)d_out;

    int BT = in_sizes[2];                   // B*T (element count)
    int chunks = BT / 4;                    // 4 t's per thread
    int blocks = (chunks + 255) / 256;      // 2048 for B=4096,T=512
    hipLaunchKernelGGL(nstep_qloss_kernel, dim3(blocks), dim3(256), 0, stream,
                       cur_q, next_q, log_p, reward, is_done, mask, out, BT);
}

// Round 5
// 162.669 us; speedup vs baseline: 1.0911x; 1.0911x over previous
//
#include <hip/hip_runtime.h>
#include <math.h>

// Problem constants (fixed by setup_inputs): B=4096, T=512, Q=4
#define T_DIM 512
#define GAMMA_F 0.997f
#define EPS_F 1e-3f
// log2(0.997)
#define LOG2_GAMMA (-0.0043345907f)

typedef float v4f __attribute__((ext_vector_type(4)));

__device__ __forceinline__ float inv_rescale_f(float x) {
    float s = (x > 0.f) ? 1.f : ((x < 0.f) ? -1.f : 0.f);
    float sqrt_arg = 1.f + 4.f * EPS_F * (fabsf(x) + 1.f + EPS_F);
    float q = (sqrtf(sqrt_arg) - 1.f) * (1.f / (2.f * EPS_F));
    return s * (q * q - 1.f);
}

__device__ __forceinline__ float rescale_f(float x) {
    return copysignf(sqrtf(fabsf(x) + 1.f) - 1.f, x) + EPS_F * x;
}

// R8: persistence + software pipeline on top of R6's ideal-traffic structure.
// Evidence: R0/R6 (one-shot waves, ideal 94MB traffic) both plateau at 2 TB/s;
// R7 (deep per-thread load stream) hit 2.9 TB/s but doubled traffic via halo
// refetch + 64B-stride uncoalesced lanes => 65us. Diagnosis: the plateau is a
// request-duty-cycle limit — one-shot waves only have loads outstanding ~40%
// of their lifetime. Fix: each block runs 4 rows (row = bid + k*1024) with
// double-buffered LDS; next row's 6 coalesced global loads are issued BEFORE
// the barrier + compute of the current row, so waves keep a continuous
// request stream and launch cost is amortized. One barrier per row (buf[c]
// written at iter k was last read at iter k-2, separated by barrier k-1).
// exp2f(s4) hoisted out of the loop. Traffic stays R6-ideal.
__global__ __launch_bounds__(512) void nstep_qloss_kernel(
    const float* __restrict__ cur_q,    // (B,T,4)
    const float* __restrict__ next_q,   // (B,T,4)
    const float* __restrict__ log_p,    // (B,T)
    const float* __restrict__ reward,   // (B,T,4)
    const float* __restrict__ is_done,  // (B,T)
    const float* __restrict__ mask,     // (B,T)
    float* __restrict__ out,            // (B,T,4)
    int nrows)
{
    __shared__ v4f   s_mr [2][T_DIM + 4];  // m * reward           (pad: 0)
    __shared__ float s_lpv[2][T_DIM + 4];  // m * (1-d) * log_p    (pad: 0)
    __shared__ float s_md [2][T_DIM + 4];  // m * (1-d)            (pad: value at T-1)

    const int t  = threadIdx.x;
    const int s4 = (t + 4 < T_DIM) ? t + 4 : T_DIM - 1;
    const float coeff = exp2f((float)s4 * LOG2_GAMMA);   // loop-invariant

    const float g1 = GAMMA_F;
    const float g2 = g1 * g1;
    const float g3 = g2 * g1;
    const float g4 = g2 * g2;
    const float LSC = GAMMA_F * (1.f / 3.f);             // extra gamma * inv_num_q

    const v4f* rew4 = (const v4f*)reward;
    const v4f* nq4  = (const v4f*)next_q;
    const v4f* cq4  = (const v4f*)cur_q;
    v4f*       out4 = (v4f*)out;

    int row = blockIdx.x;
    const int rstride = gridDim.x;
    if (row >= nrows) return;

    // ---- prologue: load first row into registers (6 coalesced loads) ----
    int base = row * T_DIM;
    float m = mask[base + t];
    float d = is_done[base + t];
    float p = log_p[base + t];
    v4f   r = rew4[base + t];
    v4f  nq = nq4[base + s4];
    v4f  cq = cq4[base + t];

    int k = 0;
    for (;;) {
        const int cur = k & 1;
        const int obase = base;

        // save epilogue operands before prefetch overwrites the regs
        const float m_c  = m;
        const v4f   nq_c = nq;
        const v4f   cq_c = cq;

        // ---- stash pre-combined window operands into LDS buf[cur] ----
        float md = m * (1.f - d);
        s_mr [cur][t] = m * r;
        s_lpv[cur][t] = md * p;
        s_md [cur][t] = md;
        if (t == T_DIM - 1) {
            v4f z; z.x = 0.f; z.y = 0.f; z.z = 0.f; z.w = 0.f;
            #pragma unroll
            for (int j = 1; j <= 4; ++j) {
                s_mr [cur][T_DIM - 1 + j] = z;
                s_lpv[cur][T_DIM - 1 + j] = 0.f;
                s_md [cur][T_DIM - 1 + j] = md;   // clamp semantics for next_term
            }
        }

        // ---- prefetch next row: loads in flight across barrier + compute ----
        const int nrow = row + rstride;
        const bool more = (nrow < nrows);
        if (more) {
            base = nrow * T_DIM;
            m  = mask[base + t];
            d  = is_done[base + t];
            p  = log_p[base + t];
            r  = rew4[base + t];
            nq = nq4[base + s4];
            cq = cq4[base + t];
        }

        __syncthreads();

        // ---- 5-tap window entirely from LDS buf[cur] ----
        v4f A0 = s_mr[cur][t];
        v4f A1 = s_mr[cur][t + 1];
        v4f A2 = s_mr[cur][t + 2];
        v4f A3 = s_mr[cur][t + 3];
        v4f A4 = s_mr[cur][t + 4];
        float l0 = s_lpv[cur][t];
        float l1 = s_lpv[cur][t + 1];
        float l2 = s_lpv[cur][t + 2];
        float l3 = s_lpv[cur][t + 3];
        float l4 = s_lpv[cur][t + 4];
        float md4 = s_md[cur][t + 4];

        // reward_sum per q (q=2 has weight 0 -> skipped)
        float a0 = A0.x, a1 = A0.y, a3 = A0.w;
        a0 = fmaf(g1, A1.x, a0); a1 = fmaf(g1, A1.y, a1); a3 = fmaf(g1, A1.w, a3);
        a0 = fmaf(g2, A2.x, a0); a1 = fmaf(g2, A2.y, a1); a3 = fmaf(g2, A2.w, a3);
        a0 = fmaf(g3, A3.x, a0); a1 = fmaf(g3, A3.y, a1); a3 = fmaf(g3, A3.w, a3);
        a0 = fmaf(g4, A4.x, a0); a1 = fmaf(g4, A4.y, a1); a3 = fmaf(g4, A4.w, a3);

        // log_p window sum (q-independent)
        float Ls = l0;
        Ls = fmaf(g1, l1, Ls);
        Ls = fmaf(g2, l2, Ls);
        Ls = fmaf(g3, l3, Ls);
        Ls = fmaf(g4, l4, Ls);
        Ls *= LSC;

        // next_term: coeff = gamma^s4 (absolute index, faithful)
        float g = coeff * md4;
        float nt0 = g * inv_rescale_f(nq_c.x);
        float nt1 = g * inv_rescale_f(nq_c.y);
        float nt3 = g * inv_rescale_f(nq_c.w);

        // q_w = {1, 0.5, 0, 2}; inv_qw = {1, 2, 0, 0.5}
        float tgt0 = rescale_f(a0 + nt0 + 1.0f * Ls);
        float tgt1 = rescale_f(a1 + nt1 + 2.0f * Ls);
        float tgt3 = rescale_f(a3 + nt3 + 0.5f * Ls);

        float hm = 0.5f * m_c;
        float e0 = cq_c.x - tgt0;
        float e1 = cq_c.y - tgt1;
        float e3 = cq_c.w - tgt3;
        v4f o;
        o.x = hm * e0 * e0;
        o.y = hm * 0.5f * e1 * e1;
        o.z = 0.f;                      // q_w[2] == 0
        o.w = hm * 2.0f * e3 * e3;
        out4[obase + t] = o;

        if (!more) break;
        row = nrow;
        ++k;
    }
}

extern "C" void kernel_launch(void* const* d_in, const int* in_sizes, int n_in,
                              void* d_out, int out_size, void* d_ws, size_t ws_size,
                              hipStream_t stream) {
    const float* cur_q   = (const float*)d_in[0];
    const float* next_q  = (const float*)d_in[1];
    const float* log_p   = (const float*)d_in[2];
    const float* reward  = (const float*)d_in[3];
    const float* is_done = (const float*)d_in[4];
    const float* mask    = (const float*)d_in[5];
    float* out = (float*)d_out;

    int BT = in_sizes[2];               // B*T (element count)
    int nrows = BT / T_DIM;             // 4096 rows
    int blocks = (nrows < 1024) ? nrows : 1024;   // 4 rows per block at full size
    hipLaunchKernelGGL(nstep_qloss_kernel, dim3(blocks), dim3(512), 0, stream,
                       cur_q, next_q, log_p, reward, is_done, mask, out, nrows);
}

// Round 6
// 160.647 us; speedup vs baseline: 1.1048x; 1.0126x over previous
//
#include <hip/hip_runtime.h>
#include <math.h>

// Problem constants (fixed by setup_inputs): B=4096, T=512, Q=4
#define T_DIM 512
#define GAMMA_F 0.997f
#define EPS_F 1e-3f
// log2(0.997)
#define LOG2_GAMMA (-0.0043345907f)

typedef float v4f __attribute__((ext_vector_type(4)));

__device__ __forceinline__ float inv_rescale_f(float x) {
    float s = (x > 0.f) ? 1.f : ((x < 0.f) ? -1.f : 0.f);
    float sqrt_arg = 1.f + 4.f * EPS_F * (fabsf(x) + 1.f + EPS_F);
    float q = (sqrtf(sqrt_arg) - 1.f) * (1.f / (2.f * EPS_F));
    return s * (q * q - 1.f);
}

__device__ __forceinline__ float rescale_f(float x) {
    return copysignf(sqrtf(fabsf(x) + 1.f) - 1.f, x) + EPS_F * x;
}

// R9: forced-MLP experiment. History: R0 (22 C loads), R6 (LDS staging), R8
// (persistent + prefetch) ALL plateau at 2 TB/s / ~48us with ideal traffic;
// R7 (deeper request stream, bad pattern) hit 2.9 TB/s. Common failure: the
// COMPILER never keeps >~1 load outstanding per wave (load->use rounds at
// minimal VGPR; ds_write immediately consumes loads; s_waitcnt vmcnt(0) is
// structurally emitted before s_barrier so prefetch-across-barrier is
// impossible at HIP level). Fix: issue all 22 loads as asm volatile
// global_load (compiler cannot sink/serialize/wait them), one explicit
// s_waitcnt vmcnt(0) + sched_barrier(0) after (rule #18), then compute.
// ~10.7 KB guaranteed outstanding per wave x ~16 waves/CU >> the ~9 KB/CU
// Little's-law requirement for 6.3 TB/s at 900cy latency.
#define GLOAD_X4(dst, ptr) \
    asm volatile("global_load_dwordx4 %0, %1, off" : "=v"(dst) : "v"(ptr))
#define GLOAD_X1(dst, ptr) \
    asm volatile("global_load_dword %0, %1, off" : "=v"(dst) : "v"(ptr))

__global__ __launch_bounds__(256) void nstep_qloss_kernel(
    const float* __restrict__ cur_q,    // (B,T,4)
    const float* __restrict__ next_q,   // (B,T,4)
    const float* __restrict__ log_p,    // (B,T)
    const float* __restrict__ reward,   // (B,T,4)
    const float* __restrict__ is_done,  // (B,T)
    const float* __restrict__ mask,     // (B,T)
    float* __restrict__ out,            // (B,T,4)
    int BT)
{
    int idx = blockIdx.x * 256 + threadIdx.x;
    if (idx >= BT) return;
    int t = idx & (T_DIM - 1);
    int base = idx - t;                 // b*T

    // ---- address math ----
    int s1 = (t + 1 < T_DIM) ? t + 1 : T_DIM - 1;
    int s2 = (t + 2 < T_DIM) ? t + 2 : T_DIM - 1;
    int s3 = (t + 3 < T_DIM) ? t + 3 : T_DIM - 1;
    int s4 = (t + 4 < T_DIM) ? t + 4 : T_DIM - 1;
    int o0 = idx;
    int o1 = base + s1, o2 = base + s2, o3 = base + s3, o4 = base + s4;

    const v4f* rew4 = (const v4f*)reward;
    const v4f* nq4  = (const v4f*)next_q;
    const v4f* cq4  = (const v4f*)cur_q;
    v4f* out4       = (v4f*)out;

    // ---- forced load block: 22 asm loads, all in flight simultaneously ----
    v4f r0, r1, r2, r3, r4, nq, cq;
    float m0, m1, m2, m3, m4;
    float d0, d1, d2, d3, d4;
    float p0, p1, p2, p3, p4;

    GLOAD_X4(r0, rew4 + o0);
    GLOAD_X4(r1, rew4 + o1);
    GLOAD_X4(r2, rew4 + o2);
    GLOAD_X4(r3, rew4 + o3);
    GLOAD_X4(r4, rew4 + o4);
    GLOAD_X4(nq, nq4 + o4);
    GLOAD_X4(cq, cq4 + o0);
    GLOAD_X1(m0, mask + o0);
    GLOAD_X1(m1, mask + o1);
    GLOAD_X1(m2, mask + o2);
    GLOAD_X1(m3, mask + o3);
    GLOAD_X1(m4, mask + o4);
    GLOAD_X1(d0, is_done + o0);
    GLOAD_X1(d1, is_done + o1);
    GLOAD_X1(d2, is_done + o2);
    GLOAD_X1(d3, is_done + o3);
    GLOAD_X1(d4, is_done + o4);
    GLOAD_X1(p0, log_p + o0);
    GLOAD_X1(p1, log_p + o1);
    GLOAD_X1(p2, log_p + o2);
    GLOAD_X1(p3, log_p + o3);
    GLOAD_X1(p4, log_p + o4);

    asm volatile("s_waitcnt vmcnt(0)" ::: "memory");
    __builtin_amdgcn_sched_barrier(0);  // rule #18: no use hoisted above the wait

    // ---- compute (identical arithmetic to the harness-passed R0/R6) ----
    float v1  = (t + 1 < T_DIM) ? 1.f : 0.f;
    float v2  = (t + 2 < T_DIM) ? 1.f : 0.f;
    float v3  = (t + 3 < T_DIM) ? 1.f : 0.f;
    float v4v = (t + 4 < T_DIM) ? 1.f : 0.f;

    const float g1 = GAMMA_F;
    const float g2 = g1 * g1;
    const float g3 = g2 * g1;
    const float g4 = g2 * g2;

    float w0 = m0;
    float w1 = v1 * g1 * m1;
    float w2 = v2 * g2 * m2;
    float w3 = v3 * g3 * m3;
    float w4 = v4v * g4 * m4;

    // reward_sum per q (q=2 has weight 0 -> only x,y,w needed)
    float a0 = w0 * r0.x; float a1 = w0 * r0.y; float a2 = w0 * r0.z; float a3 = w0 * r0.w;
    a0 = fmaf(w1, r1.x, a0); a1 = fmaf(w1, r1.y, a1); a2 = fmaf(w1, r1.z, a2); a3 = fmaf(w1, r1.w, a3);
    a0 = fmaf(w2, r2.x, a0); a1 = fmaf(w2, r2.y, a1); a2 = fmaf(w2, r2.z, a2); a3 = fmaf(w2, r2.w, a3);
    a0 = fmaf(w3, r3.x, a0); a1 = fmaf(w3, r3.y, a1); a2 = fmaf(w3, r3.z, a2); a3 = fmaf(w3, r3.w, a3);
    a0 = fmaf(w4, r4.x, a0); a1 = fmaf(w4, r4.y, a1); a2 = fmaf(w4, r4.z, a2); a3 = fmaf(w4, r4.w, a3);

    // log_p window sum (q-independent)
    float Ls = w0 * (1.f - d0) * p0;
    Ls = fmaf(w1, (1.f - d1) * p1, Ls);
    Ls = fmaf(w2, (1.f - d2) * p2, Ls);
    Ls = fmaf(w3, (1.f - d3) * p3, Ls);
    Ls = fmaf(w4, (1.f - d4) * p4, Ls);
    Ls *= GAMMA_F * (1.f / 3.f);        // extra gamma factor * inv_num_q

    // next_term: coeff = gamma^i (absolute index, faithful), i = s4
    float coeff = exp2f((float)s4 * LOG2_GAMMA);
    float g = coeff * m4 * (1.f - d4);
    float nt0 = g * inv_rescale_f(nq.x);
    float nt1 = g * inv_rescale_f(nq.y);
    float nt3 = g * inv_rescale_f(nq.w);

    // q_w = {1, 0.5, 0, 2}; inv_qw = {1, 2, 0, 0.5}
    float tgt0 = rescale_f(a0 + nt0 + 1.0f * Ls);
    float tgt1 = rescale_f(a1 + nt1 + 2.0f * Ls);
    float tgt3 = rescale_f(a3 + nt3 + 0.5f * Ls);
    (void)a2;

    float hm = 0.5f * m0;
    float e0 = cq.x - tgt0;
    float e1 = cq.y - tgt1;
    float e3 = cq.w - tgt3;
    v4f o;
    o.x = hm * e0 * e0;
    o.y = hm * 0.5f * e1 * e1;
    o.z = 0.f;                          // q_w[2] == 0
    o.w = hm * 2.0f * e3 * e3;
    out4[idx] = o;
}

extern "C" void kernel_launch(void* const* d_in, const int* in_sizes, int n_in,
                              void* d_out, int out_size, void* d_ws, size_t ws_size,
                              hipStream_t stream) {
    const float* cur_q   = (const float*)d_in[0];
    const float* next_q  = (const float*)d_in[1];
    const float* log_p   = (const float*)d_in[2];
    const float* reward  = (const float*)d_in[3];
    const float* is_done = (const float*)d_in[4];
    const float* mask    = (const float*)d_in[5];
    float* out = (float*)d_out;

    int BT = in_sizes[2];               // B*T
    int blocks = (BT + 255) / 256;
    hipLaunchKernelGGL(nstep_qloss_kernel, dim3(blocks), dim3(256), 0, stream,
                       cur_q, next_q, log_p, reward, is_done, mask, out, BT);
}